// Round 1
// baseline (76.667 us; speedup 1.0000x reference)
//
#include <hip/hip_runtime.h>
#include <math.h>

#define BLOCK 128

__device__ __forceinline__ float fast_rcp(float x) {
    return __builtin_amdgcn_rcpf(x);
}
__device__ __forceinline__ float med3f(float a, float b, float c) {
    return __builtin_amdgcn_fmed3f(a, b, c);   // median == clamp when lo<=hi
}
// HW sin/cos: v_sin_f32/v_cos_f32 take revolutions; |arg| < 1 rev here -> full accuracy
__device__ __forceinline__ float fsin(float x) {
    return __builtin_amdgcn_sinf(x * 0.15915494309189535f);
}
__device__ __forceinline__ float fcos(float x) {
    return __builtin_amdgcn_cosf(x * 0.15915494309189535f);
}

// L1 "diamond" pseudo-angle: strictly monotone in atan2(y,x); (0,0) -> 0.
__device__ __forceinline__ float pseudo_angle(float x, float y) {
    float d = fabsf(x) + fabsf(y);
    float p = (d == 0.f) ? 1.f : x * fast_rcp(d);
    return (y < 0.f) ? (p - 1.f) : (1.f - p);
}

__launch_bounds__(BLOCK)
__global__ void giou_kernel(const float* __restrict__ pred,
                            const float* __restrict__ target,
                            const float* __restrict__ weight,
                            float* __restrict__ partials, int N) {
    // enclose-sort scratch only; per-thread slots, slot-major -> conflict-free
    __shared__ float2 bufA[8][BLOCK];   // 8 KiB

    int tid = threadIdx.x;
    long gi = (long)blockIdx.x * BLOCK + tid;
    int i = (gi < (long)N) ? (int)gi : (N - 1);

    float p[5], q[5];
#pragma unroll
    for (int j = 0; j < 5; ++j) p[j] = pred[i * 5 + j];
#pragma unroll
    for (int j = 0; j < 5; ++j) q[j] = target[i * 5 + j];
    float wgt = weight[i];

    // ---- everything in box2's local frame (areas are rotation-invariant) ----
    float cq = fcos(q[4]), sq = fsin(q[4]);
    float dang = p[4] - q[4];
    float cd = fcos(dang), sd = fsin(dang);
    float hw = 0.5f * q[2], hh = 0.5f * q[3];   // box2 = [-hw,hw]x[-hh,hh]
    float dxc = p[0] - q[0], dyc = p[1] - q[1];
    float tx = dxc * cq + dyc * sq;
    float ty = -dxc * sq + dyc * cq;
    float ax_ = 0.5f * p[2] * cd, ay_ = 0.5f * p[2] * sd;   // 0.5*w1*(cd,sd)
    float bx_ = -0.5f * p[3] * sd, by_ = 0.5f * p[3] * cd;  // 0.5*h1*(-sd,cd)

    // box1 corners in frame, CCW (shoelace of this order is +area), same
    // (dx,dy) pattern as reference
    float qx[4], qy[4];
    qx[0] = tx + ax_ + bx_; qy[0] = ty + ay_ + by_;
    qx[1] = tx - ax_ + bx_; qy[1] = ty - ay_ + by_;
    qx[2] = tx - ax_ - bx_; qy[2] = ty - ay_ - by_;
    qx[3] = tx + ax_ - bx_; qy[3] = ty + ay_ - by_;

    // ---- overlap via Green's theorem, no polygon construction ----
    // Area(Q ∩ R) = Σ_edges dy * ∫ clamp(x(t), -hw, hw) dt over t-range where
    // y(t) ∈ [-hh, hh].  Inner integral of a clamped linear fn is closed-form:
    // saturated piece + exact midpoint-rule linear piece + saturated piece.
    // NaN paths (rcp(0) with zero numerator) are absorbed by IEEE min/max and
    // by taking saturation values as clamp(x(tin))/clamp(x(tout)) (finite).
    float acc = 0.f;
#pragma unroll
    for (int e = 0; e < 4; ++e) {
        int en = (e + 1) & 3;
        float xa = qx[e], ya = qy[e];
        float dx = qx[en] - xa, dy = qy[en] - ya;
        // t-interval where y ∈ [-hh, hh], clipped to [0,1]
        float rdy = fast_rcp(dy);
        float tA = (-hh - ya) * rdy;
        float tB = ( hh - ya) * rdy;
        float tin  = med3f(fminf(tA, tB), 0.f, 1.f);
        float tout = med3f(fmaxf(tA, tB), 0.f, 1.f);
        bool dz = (dy == 0.f);              // guard 0*inf=NaN when ya==±hh
        tin  = dz ? 0.f : tin;
        tout = dz ? 0.f : tout;
        // x-clamp breakpoints inside [tin, tout]
        float rdx = fast_rcp(dx);
        float tL = (-hw - xa) * rdx;
        float tH = ( hw - xa) * rdx;
        float u0 = med3f(fminf(tL, tH), tin, tout);
        float u1 = med3f(fmaxf(tL, tH), tin, tout);
        // saturation values = clamped x at the window ends (finite always)
        float V0 = med3f(fmaf(tin,  dx, xa), -hw, hw);
        float V1 = med3f(fmaf(tout, dx, xa), -hw, hw);
        // middle (linear) piece: exact via midpoint rule
        float mid = (u1 - u0) * fmaf(0.5f * (u0 + u1), dx, xa);
        float inner = fmaf(V0, u0 - tin, mid) + V1 * (tout - u1);
        acc = fmaf(dy, inner, acc);
    }
    float overlap = fabsf(acc);

    // ---- enclose: 8 frame points, reference-faithful sorted shoelace ----
    float enc;
    {
        float px8[8], py8[8];
#pragma unroll
        for (int j = 0; j < 4; ++j) { px8[j] = qx[j]; py8[j] = qy[j]; }
        px8[4] = hw;  py8[4] = hh;
        px8[5] = -hw; py8[5] = hh;
        px8[6] = -hw; py8[6] = -hh;
        px8[7] = hw;  py8[7] = -hh;
        // analytic mean: quad corners sum to 4*(tx,ty), rect corners to 0
        float mx = 0.5f * tx, my = 0.5f * ty;
        float ang[8];
#pragma unroll
        for (int j = 0; j < 8; ++j) ang[j] = pseudo_angle(px8[j] - mx, py8[j] - my);
        // stable rank via 28 pairwise compares: r[j] = #{k<j: a[k]<=a[j]} +
        // #{k>j: a[k]<a[j]}  (identical to stable argsort of reference)
        int r[8];
#pragma unroll
        for (int j = 0; j < 8; ++j) r[j] = j;
#pragma unroll
        for (int j = 0; j < 8; ++j)
#pragma unroll
            for (int k = j + 1; k < 8; ++k) {
                int b = (ang[k] < ang[j]) ? 1 : 0;
                r[j] += b;
                r[k] -= b;
            }
        // per-thread LDS scatter (single round trip), slot-major layout
#pragma unroll
        for (int j = 0; j < 8; ++j) bufA[r[j]][tid] = make_float2(px8[j], py8[j]);
        float sx0[8], sy0[8];
#pragma unroll
        for (int k = 0; k < 8; ++k) {
            float2 v = bufA[k][tid];
            sx0[k] = v.x; sy0[k] = v.y;
        }
        float acc2 = 0.f;
#pragma unroll
        for (int k = 0; k < 8; ++k) {
            int kn = (k + 1) & 7;
            acc2 += sx0[k] * sy0[kn] - sy0[k] * sx0[kn];
        }
        enc = 0.5f * fabsf(acc2);
    }

    // ---- GIoU loss ----
    float area1 = p[2] * p[3];
    float area2 = q[2] * q[3];
    float uni = area1 + area2 - overlap + 1e-6f;
    float iou = fmaxf(overlap / uni, 1e-6f);
    float giou = iou - (enc - uni) / enc;
    float loss = (1.f - giou) * wgt;
    if (gi >= (long)N) loss = 0.f;

    // wave-64 reduce -> one plain store per wave (no global atomics)
#pragma unroll
    for (int off = 32; off > 0; off >>= 1)
        loss += __shfl_down(loss, off, 64);
    if ((tid & 63) == 0)
        partials[blockIdx.x * (BLOCK / 64) + (tid >> 6)] = loss;
}

// Deterministic final reduce: one 1024-thread block over the partials.
__launch_bounds__(1024)
__global__ void reduce_kernel(const float* __restrict__ partials,
                              float* __restrict__ out, int nparts, float scale) {
    __shared__ float acc[16];
    int tid = threadIdx.x;
    float s = 0.f;
    for (int j = tid; j < nparts; j += 1024) s += partials[j];
#pragma unroll
    for (int off = 32; off > 0; off >>= 1)
        s += __shfl_down(s, off, 64);
    if ((tid & 63) == 0) acc[tid >> 6] = s;
    __syncthreads();
    if (tid == 0) {
        float t = 0.f;
#pragma unroll
        for (int k = 0; k < 16; ++k) t += acc[k];
        out[0] = t * scale;
    }
}

extern "C" void kernel_launch(void* const* d_in, const int* in_sizes, int n_in,
                              void* d_out, int out_size, void* d_ws, size_t ws_size,
                              hipStream_t stream) {
    const float* pred   = (const float*)d_in[0];
    const float* target = (const float*)d_in[1];
    const float* weight = (const float*)d_in[2];
    float* out = (float*)d_out;
    float* ws  = (float*)d_ws;
    int N = in_sizes[0] / 5;

    int nblocks = (N + BLOCK - 1) / BLOCK;
    int nparts = nblocks * (BLOCK / 64);
    giou_kernel<<<nblocks, BLOCK, 0, stream>>>(pred, target, weight, ws, N);
    reduce_kernel<<<1, 1024, 0, stream>>>(ws, out, nparts, 1.0f / (float)N);
}